// Round 1
// baseline (722.403 us; speedup 1.0000x reference)
//
#include <hip/hip_runtime.h>

// CausalAttention: B=4, S=4096, D=1024 (single head, head_dim=1024)
// Pipeline: cast f32->bf16 -> fused QKV GEMM (V written transposed) -> flash attn (no-max softmax)
// ws layout (u16 elems): Wqkv[3*1024*1024] | Xbf[16384*1024] | Q[16384*1024] | K[16384*1024] | VT[4*1024*4096]
// total ws = 140,509,184 bytes (~134 MiB)

typedef unsigned short u16;
typedef __attribute__((ext_vector_type(8))) short bf16x8;   // 8 bf16 = 4 VGPR (MFMA A/B frag)
typedef __attribute__((ext_vector_type(4))) float f32x4;    // MFMA C/D frag
typedef __attribute__((ext_vector_type(8))) unsigned short u16x8;

__device__ __forceinline__ u16 f2bf(float f) {
  union { float f; unsigned u; } v; v.f = f;
  unsigned r = v.u + 0x7FFFu + ((v.u >> 16) & 1u);  // RNE
  return (u16)(r >> 16);
}
__device__ __forceinline__ float bf2f(u16 h) {
  union { unsigned u; float f; } v; v.u = ((unsigned)h) << 16;
  return v.f;
}
__device__ __forceinline__ f32x4 mfma16(bf16x8 a, bf16x8 b, f32x4 c) {
  return __builtin_amdgcn_mfma_f32_16x16x32_bf16(a, b, c, 0, 0, 0);
}

// ---------------- cast f32 -> bf16, 8 elems/thread ----------------
__global__ __launch_bounds__(256)
void cast_f32_bf16(const float* __restrict__ src, u16* __restrict__ dst, int n8) {
  int i = blockIdx.x * 256 + threadIdx.x;
  if (i >= n8) return;
  const float4* s4 = (const float4*)src;
  float4 a = s4[2*i], b = s4[2*i+1];
  u16x8 o;
  o[0]=f2bf(a.x); o[1]=f2bf(a.y); o[2]=f2bf(a.z); o[3]=f2bf(a.w);
  o[4]=f2bf(b.x); o[5]=f2bf(b.y); o[6]=f2bf(b.z); o[7]=f2bf(b.w);
  ((u16x8*)dst)[i] = o;
}

// ---------------- fused QKV GEMM ----------------
// C[m][n] = sum_k X[m][k] * W[n][k]   (NT gemm, both row-major k-contiguous)
// M=16384, N=3072 (Q|K|V), K=1024. Tile 128x128, BK=64, 256 thr (4 waves),
// each wave = 64x64 quadrant = 4x4 frags of 16x16.
// LDS tiles stored as 16B chunks with chunk-col XOR (row&7) swizzle -> frag reads 2-way (free).
// V output (which==2) written TRANSPOSED: VT[b][d][s].
__global__ __launch_bounds__(256)
void qkv_gemm(const u16* __restrict__ X, const u16* __restrict__ W,
              u16* __restrict__ Qo, u16* __restrict__ Ko, u16* __restrict__ VTo) {
  __shared__ u16 At[128 * 64];
  __shared__ u16 Bt[128 * 64];
  const int tid = threadIdx.x;
  const int w = tid >> 6, lane = tid & 63;
  const int g = lane >> 4, c16 = lane & 15;
  const int wr = w >> 1, wc = w & 1;
  const int M0 = blockIdx.x * 128;
  const int N0 = blockIdx.y * 128;

  f32x4 acc[4][4] = {};

  for (int t = 0; t < 16; ++t) {
    const int k0 = t * 64;
    __syncthreads();
    uint4 ra[4], rb[4];
#pragma unroll
    for (int i = 0; i < 4; ++i) {
      int ci = i * 256 + tid;            // linear 16B chunk id, 1024 chunks/tile
      int r  = ci >> 3;                  // row 0..127
      int c  = (ci & 7) ^ (r & 7);       // swizzled source chunk col
      ra[i] = *(const uint4*)(X + (size_t)(M0 + r) * 1024 + k0 + c * 8);
      rb[i] = *(const uint4*)(W + (size_t)(N0 + r) * 1024 + k0 + c * 8);
    }
#pragma unroll
    for (int i = 0; i < 4; ++i) {
      int ci = i * 256 + tid;
      *(uint4*)&At[(size_t)ci * 8] = ra[i];
      *(uint4*)&Bt[(size_t)ci * 8] = rb[i];
    }
    __syncthreads();
#pragma unroll
    for (int dk = 0; dk < 2; ++dk) {
      bf16x8 af[4], bfr[4];
#pragma unroll
      for (int m = 0; m < 4; ++m) {
        int row = wr * 64 + m * 16 + c16;
        int ch  = dk * 4 + g;
        af[m] = *(const bf16x8*)&At[row * 64 + ((ch ^ (row & 7)) * 8)];
      }
#pragma unroll
      for (int n = 0; n < 4; ++n) {
        int row = wc * 64 + n * 16 + c16;
        int ch  = dk * 4 + g;
        bfr[n] = *(const bf16x8*)&Bt[row * 64 + ((ch ^ (row & 7)) * 8)];
      }
#pragma unroll
      for (int m = 0; m < 4; ++m)
#pragma unroll
        for (int n = 0; n < 4; ++n)
          acc[m][n] = mfma16(af[m], bfr[n], acc[m][n]);
    }
  }

  const int which = N0 >> 10;        // 0=Q, 1=K, 2=V
  const int colbase = N0 & 1023;
#pragma unroll
  for (int m = 0; m < 4; ++m) {
#pragma unroll
    for (int n = 0; n < 4; ++n) {
#pragma unroll
      for (int r = 0; r < 4; ++r) {
        int gm  = M0 + wr * 64 + m * 16 + 4 * g + r;  // D row = 4*(lane>>4)+reg
        int col = colbase + wc * 64 + n * 16 + c16;   // D col = lane&15
        u16 hv = f2bf(acc[m][n][r]);
        if (which == 0) {
          Qo[(size_t)gm * 1024 + col] = hv;
        } else if (which == 1) {
          Ko[(size_t)gm * 1024 + col] = hv;
        } else {
          int b = gm >> 12, s = gm & 4095;
          VTo[((size_t)((b << 10) + col)) * 4096 + s] = hv;
        }
      }
    }
  }
}

// ---------------- causal attention (no-max flash) ----------------
// Per WG: batch b, 32 q-rows. 512 thr = 8 waves.
// S-phase: wave (kh = w&1, dq = w>>1): S-partial[32q x 16kv] over d-quarter dq*256,
//   Q frags in registers (loaded once), K tile in LDS (read exactly once per iter).
// P-phase: 512 thr compute P = exp(S/32) (causal-masked), row-sums into l_lds.
// PV-phase: wave w owns d-slice [w*128, w*128+128); V^T tile in LDS (d-subtiled layout).
// No softmax max subtraction: max logit = ||q||^2/32 <= ~17 -> exp() safe in f32/bf16.
__global__ __launch_bounds__(512, 2)
void attn_kernel(const u16* __restrict__ Q, const u16* __restrict__ K,
                 const u16* __restrict__ VT, float* __restrict__ Out) {
  __shared__ u16 kv_lds[32 * 1024];          // 64KB, reused K-phase then V-phase
  __shared__ float s_part[4][32][33];        // partial S per d-quarter (padded)
  __shared__ u16 p_lds[32 * 40];             // P bf16, rows padded to 40
  __shared__ float l_lds[32];

  const int tid = threadIdx.x;
  const int w = tid >> 6, lane = tid & 63;
  const int g = lane >> 4, c16 = lane & 15;
  const int b  = blockIdx.x & 3;
  const int qb = 127 - (blockIdx.x >> 2);    // heavy blocks first
  const int qs = qb * 32;
  const int kh = w & 1, dq = w >> 1;

  const u16* Qb  = Q  + (size_t)b * 4096 * 1024;
  const u16* Kb  = K  + (size_t)b * 4096 * 1024;
  const u16* VTb = VT + (size_t)b * 1024 * 4096;

  // Q fragments: rows qs + qh*16 + (lane&15), d-quarter dq*256 (A-frag: row=lane&15, k=8*(lane>>4)+j)
  bf16x8 qfrag[2][8];
#pragma unroll
  for (int qh = 0; qh < 2; ++qh)
#pragma unroll
    for (int dk = 0; dk < 8; ++dk)
      qfrag[qh][dk] = *(const bf16x8*)(Qb + (size_t)(qs + qh * 16 + c16) * 1024
                                       + dq * 256 + dk * 32 + g * 8);

  f32x4 oacc[2][8] = {};
  if (tid < 32) l_lds[tid] = 0.f;

  const int qrow_p = tid >> 4;       // P-phase row (0..31)
  const int kk     = tid & 15;
  const int gq     = qs + qrow_p;

  for (int j = 0; j <= qb; ++j) {
    const int kv0 = j * 32;
    __syncthreads();                                   // bar1: prev PV done with kv_lds/p_lds
    // ---- stage K tile [32][1024], chunk-swizzled (low3 of chunk-col ^ row) ----
    uint4 rk[8];
#pragma unroll
    for (int i = 0; i < 8; ++i) {
      int ci = i * 512 + tid;                          // 4096 chunks
      int r  = ci >> 7;
      int c  = (ci & 127) ^ (r & 7);
      rk[i] = *(const uint4*)(Kb + (size_t)(kv0 + r) * 1024 + c * 8);
    }
#pragma unroll
    for (int i = 0; i < 8; ++i)
      *(uint4*)&kv_lds[(size_t)(i * 512 + tid) * 8] = rk[i];
    __syncthreads();                                   // bar2: K ready
    // ---- S-phase ----
    f32x4 sacc[2] = {};
#pragma unroll
    for (int dk = 0; dk < 8; ++dk) {
      int kvrow = kh * 16 + c16;
      int ch    = dq * 32 + dk * 4 + g;
      bf16x8 kf = *(const bf16x8*)&kv_lds[kvrow * 1024 + ((ch ^ (kvrow & 7)) * 8)];
      sacc[0] = mfma16(qfrag[0][dk], kf, sacc[0]);
      sacc[1] = mfma16(qfrag[1][dk], kf, sacc[1]);
    }
#pragma unroll
    for (int qh = 0; qh < 2; ++qh)
#pragma unroll
      for (int r = 0; r < 4; ++r)
        s_part[dq][qh * 16 + 4 * g + r][kh * 16 + c16] = sacc[qh][r];
    __syncthreads();                                   // bar3: s_part ready, kv_lds free
    // ---- issue V loads early (hide under P-phase) ----
    uint4 rv[8];
#pragma unroll
    for (int i = 0; i < 8; ++i) {
      int ci = i * 512 + tid;
      int d  = ((ci >> 6) << 4) + (ci & 15);           // d-subtiled layout
      int c  = (ci >> 4) & 3;
      rv[i] = *(const uint4*)(VTb + (size_t)d * 4096 + kv0 + c * 8);
    }
    // ---- P-phase ----
    {
      float psum = 0.f;
#pragma unroll
      for (int h = 0; h < 2; ++h) {
        int kcol = kk + h * 16;
        float s = s_part[0][qrow_p][kcol] + s_part[1][qrow_p][kcol]
                + s_part[2][qrow_p][kcol] + s_part[3][qrow_p][kcol];
        s *= 0.03125f;                                 // 1/sqrt(1024)
        float p = (kv0 + kcol <= gq) ? __expf(s) : 0.f;
        u16 pb = f2bf(p);
        p_lds[qrow_p * 40 + kcol] = pb;
        psum += bf2f(pb);                              // l from rounded P (exact normalization)
      }
#pragma unroll
      for (int off = 1; off < 16; off <<= 1)
        psum += __shfl_xor(psum, off, 64);
      if (kk == 0) l_lds[qrow_p] += psum;
    }
    // ---- write V tile to LDS: position p holds VT[(p>>6)*16 + (p&15)][chunk (p>>4)&3] ----
#pragma unroll
    for (int i = 0; i < 8; ++i)
      *(uint4*)&kv_lds[(size_t)(i * 512 + tid) * 8] = rv[i];
    __syncthreads();                                   // bar4: P + V ready
    // ---- PV-phase: O[q][dslice] += P[q][kv] * V[kv][d] ----
    bf16x8 pa0 = *(const bf16x8*)&p_lds[(0  + c16) * 40 + g * 8];
    bf16x8 pa1 = *(const bf16x8*)&p_lds[(16 + c16) * 40 + g * 8];
#pragma unroll
    for (int f = 0; f < 8; ++f) {
      int dcol = w * 128 + f * 16 + c16;
      int pos  = (dcol >> 4) * 64 + g * 16 + (dcol & 15);
      bf16x8 vf = *(const bf16x8*)&kv_lds[(size_t)pos * 8];
      oacc[0][f] = mfma16(pa0, vf, oacc[0][f]);
      oacc[1][f] = mfma16(pa1, vf, oacc[1][f]);
    }
  }

  // ---- epilogue: normalize and store f32 ----
  float* Ob = Out + (size_t)b * 4096 * 1024;
#pragma unroll
  for (int qh = 0; qh < 2; ++qh) {
#pragma unroll
    for (int r = 0; r < 4; ++r) {
      int ql = qh * 16 + 4 * g + r;
      float linv = 1.f / l_lds[ql];
#pragma unroll
      for (int f = 0; f < 8; ++f)
        Ob[(size_t)(qs + ql) * 1024 + w * 128 + f * 16 + c16] = oacc[qh][f][r] * linv;
    }
  }
}

extern "C" void kernel_launch(void* const* d_in, const int* in_sizes, int n_in,
                              void* d_out, int out_size, void* d_ws, size_t ws_size,
                              hipStream_t stream) {
  const float* x  = (const float*)d_in[0];
  const float* Wq = (const float*)d_in[1];
  const float* Wk = (const float*)d_in[2];
  const float* Wv = (const float*)d_in[3];
  float* out = (float*)d_out;

  u16* ws    = (u16*)d_ws;
  u16* wWqkv = ws;                                   // 3*1024*1024
  u16* wX    = wWqkv + (size_t)3 * 1024 * 1024;      // 16384*1024
  u16* wQ    = wX + (size_t)16384 * 1024;
  u16* wK    = wQ + (size_t)16384 * 1024;
  u16* wVT   = wK + (size_t)16384 * 1024;            // [4][1024][4096]

  cast_f32_bf16<<<dim3(8192), 256, 0, stream>>>(x, wX, 16777216 / 8);
  cast_f32_bf16<<<dim3(512), 256, 0, stream>>>(Wq, wWqkv,                 1048576 / 8);
  cast_f32_bf16<<<dim3(512), 256, 0, stream>>>(Wk, wWqkv + 1048576,       1048576 / 8);
  cast_f32_bf16<<<dim3(512), 256, 0, stream>>>(Wv, wWqkv + 2 * 1048576,   1048576 / 8);

  qkv_gemm<<<dim3(128, 24), 256, 0, stream>>>(wX, wWqkv, wQ, wK, wVT);

  attn_kernel<<<dim3(512), 512, 0, stream>>>(wQ, wK, wVT, out);
}